// Round 1
// 182.167 us; speedup vs baseline: 1.0102x; 1.0102x over previous
//
#include <hip/hip_runtime.h>

#define C_BINS 9
#define H_DIM 260
#define WDIM 346
#define B_DIM 16
#define N_PER_B 32768
#define HIDDEN 100
#define NEG_SLOPE 0.1f
#define WH (WDIM * H_DIM)                         /* 89,960 */
#define NUM_VOXELS (2 * C_BINS * WH * B_DIM)      /* 25,908,480 */
#define TABLE_N 16384                             /* intervals over [-1,1]; TABLE_N+1 entries */
#define HALF_N (TABLE_N / 2)                      /* 8192 */
#define BIN_SHIFT (TABLE_N / 16)                  /* table shift per bin = 1024, exact in fp32 */
#define T9_STRIDE 12                              /* 9 bins padded to 12 floats = 48 B (16B-aligned) */

#define ROWS_PER_TILE 5                           /* 52 tiles cover 260 rows exactly */
#define TILES_PER_BP 52
#define LBUCKETS (2 * TILES_PER_BP)               /* 104 local buckets (pol, ytile) */
#define NBUCKETS (B_DIM * LBUCKETS)               /* 1664 global buckets */
#define BUCKET_CAP 512                            /* mean 315, sigma ~18 -> 11 sigma margin */
#define EV_PER_BLOCK 1024                         /* divides 32768; 512 blocks -> 2 blocks/CU */
#define TILE_ELEMS (C_BINS * ROWS_PER_TILE * WDIM)/* 15,570 floats = 62,280 B LDS */
#define ROW_F2 (ROWS_PER_TILE * WDIM / 2)         /* 865 float2 per bin-chunk */

// workspace layout (bytes)
#define WS_TABLE_OFF 0                                     /* (TABLE_N+1)*4 = 65,540 */
#define WS_COUNT_OFF 66048                                 /* NBUCKETS*4 = 6,656 */
#define WS_T9_OFF    73728                                 /* (HALF_N+1)*12*4 = 393,264 */
#define WS_REC_OFF   467968
#define WS_REC_SZ    ((size_t)NBUCKETS * BUCKET_CAP * 8)   /* 6,815,744 */
#define WS_NEEDED    (WS_REC_OFF + WS_REC_SZ)              /* ~7.28 MB */

// ---------------------------------------------------------------------------
// Kernel 1: tabulate f(u) = MLP(u) on a uniform grid over [-1, 1].
// 8 threads/entry: quad over k-rows x duo over j-halves (j0 = 0 or 52 keeps
// LDS rows 16B-aligned for ds_read_b128). 32 entries/block, grid 512+1 ->
// exactly 2 blocks/CU, 2 waves/SIMD (old 257-block layout was 1 wave/SIMD
// with a 2x full-block straggler on one CU).
// Also scatters each entry into the packed interp layout
// T9[r][i] = table[r + 8192 - 1024*i]  (r in [0,8192], 12-float rows),
// so tile_kernel reads ONE contiguous 96 B block per record instead of
// 18 loads at 4 KB stride (which thrash L1 sets).
// Block 0 also zeros the bucket counters.
// ---------------------------------------------------------------------------
__global__ __launch_bounds__(256) void build_table_kernel(
    const float* __restrict__ W1, const float* __restrict__ b1,
    const float* __restrict__ W2, const float* __restrict__ b2,
    const float* __restrict__ W3, const float* __restrict__ b3,
    float* __restrict__ table, float* __restrict__ t9,
    unsigned int* __restrict__ counts, int write_t9)
{
    __shared__ __align__(16) float sW2[HIDDEN * HIDDEN + 8]; /* +8 zero pad for j-overrun */
    __shared__ float sW1[HIDDEN], sb1[HIDDEN], sb2[HIDDEN], sW3[HIDDEN];
    const int tid = threadIdx.x;

    if (write_t9 && blockIdx.x == 0) {
        for (int i = tid; i < NBUCKETS; i += 256) counts[i] = 0u;
    }

    {
        const float4* __restrict__ src = (const float4*)W2;
        float4* dst = (float4*)sW2;
        for (int i = tid; i < (HIDDEN * HIDDEN) / 4; i += 256) dst[i] = src[i];
    }
    if (tid < 8) sW2[HIDDEN * HIDDEN + tid] = 0.0f;   /* pad must be finite (0*NaN = NaN) */
    if (tid < HIDDEN) {
        sW1[tid] = W1[tid];
        sb1[tid] = b1[tid];
        sb2[tid] = b2[tid];
        sW3[tid] = W3[tid];
    }
    __syncthreads();

    const int entry_local = tid >> 3;            /* 32 entries per block */
    const int o  = tid & 7;
    const int q  = o & 3;                        /* k-residue */
    const int j0 = (o >> 2) * 52;                /* j-half start: 0 or 52 (both %4==0) */
    const int g  = blockIdx.x * 32 + entry_local;
    if (g > TABLE_N) return;
    const float u = -1.0f + (2.0f / (float)TABLE_N) * (float)g;

    float h1[52];
#pragma unroll
    for (int j = 0; j < 52; ++j) {
        const int jj = j0 + j;
        float v = (jj < HIDDEN) ? fmaf(u, sW1[jj], sb1[jj]) : 0.0f;
        h1[j] = (v >= 0.0f) ? v : NEG_SLOPE * v;
    }

    float acc = 0.0f;
    for (int k = q; k < HIDDEN; k += 4) {
        const float* __restrict__ row = &sW2[k * HIDDEN + j0];
        float a0 = 0.f, a1 = 0.f, a2 = 0.f, a3 = 0.f;
#pragma unroll
        for (int j = 0; j < 52; j += 4) {
            a0 = fmaf(row[j + 0], h1[j + 0], a0);
            a1 = fmaf(row[j + 1], h1[j + 1], a1);
            a2 = fmaf(row[j + 2], h1[j + 2], a2);
            a3 = fmaf(row[j + 3], h1[j + 3], a3);
        }
        float part = (a0 + a1) + (a2 + a3);
        part += __shfl_xor(part, 4);             /* combine j-halves (lanes o, o^4) */
        float a = sb2[k] + part;
        a = (a >= 0.0f) ? a : NEG_SLOPE * a;
        acc = fmaf(a, sW3[k], acc);
    }
    acc += __shfl_xor(acc, 1);                   /* combine k-quads */
    acc += __shfl_xor(acc, 2);
    if (o == 0) {
        const float val = acc + b3[0];
        table[g] = val;
        if (write_t9) {
#pragma unroll
            for (int i = 0; i < C_BINS; ++i) {
                const int r = g - HALF_N + BIN_SHIFT * i;
                if (r >= 0 && r <= HALF_N) t9[r * T9_STRIDE + i] = val;
            }
        }
    }
}

// ---------------------------------------------------------------------------
// Kernel 2a: block-aggregated counting scatter.
// One block owns 1024 consecutive events (one batch -> 104 local buckets;
// 512 blocks -> 2 blocks/CU). Events now loaded 4-consecutive per thread via
// int4/float4 (record order within a bucket is irrelevant: output is a sum).
// LDS count -> prefix -> ONE global atomicAdd per non-empty bucket ->
// records staged bucket-sorted in LDS -> contiguous ~10-record copy-out.
// ---------------------------------------------------------------------------
__global__ __launch_bounds__(256) void bucket_kernel(
    const int* __restrict__ xs, const int* __restrict__ ys,
    const float* __restrict__ ts, const int* __restrict__ ps,
    unsigned int* __restrict__ counts,
    unsigned long long* __restrict__ records, int E)
{
    __shared__ unsigned lcnt[LBUCKETS];
    __shared__ unsigned lpre[LBUCKETS];
    __shared__ unsigned gbase[LBUCKETS];
    __shared__ unsigned scan[2][128];
    __shared__ unsigned long long stage[EV_PER_BLOCK];
    __shared__ unsigned char slb[EV_PER_BLOCK];

    const int tid = threadIdx.x;
    const int e0  = blockIdx.x * EV_PER_BLOCK;
    const int b   = e0 >> 15;   /* whole block lies in one batch: 1024 | 32768 */

    for (int i = tid; i < LBUCKETS; i += 256) lcnt[i] = 0;
    __syncthreads();

    int lb[4];
    unsigned rank[4];
    unsigned long long rec[4];
    const int eb = e0 + tid * 4;
    if (eb + 3 < E) {
        const int v4 = (e0 >> 2) + tid;
        const int4   xv = ((const int4*)xs)[v4];
        const int4   yv = ((const int4*)ys)[v4];
        const int4   pv = ((const int4*)ps)[v4];
        const float4 tv = ((const float4*)ts)[v4];
        const int   xa[4] = {xv.x, xv.y, xv.z, xv.w};
        const int   ya[4] = {yv.x, yv.y, yv.z, yv.w};
        const int   pa[4] = {pv.x, pv.y, pv.z, pv.w};
        const float ta[4] = {tv.x, tv.y, tv.z, tv.w};
#pragma unroll
        for (int j = 0; j < 4; ++j) {
            const int yt = ya[j] / ROWS_PER_TILE;
            const int yl = ya[j] - yt * ROWS_PER_TILE;
            lb[j]  = pa[j] * TILES_PER_BP + yt;
            rec[j] = ((unsigned long long)__float_as_uint(ta[j]) << 32)
                   | (unsigned)(yl * WDIM + xa[j]);
            rank[j] = atomicAdd(&lcnt[lb[j]], 1u);
        }
    } else {
#pragma unroll
        for (int j = 0; j < 4; ++j) {
            const int e = eb + j;
            if (e < E) {
                const int   x = xs[e];
                const int   y = ys[e];
                const int   p = ps[e];
                const float t = ts[e];
                const int  yt = y / ROWS_PER_TILE;
                const int  yl = y - yt * ROWS_PER_TILE;
                lb[j]  = p * TILES_PER_BP + yt;
                rec[j] = ((unsigned long long)__float_as_uint(t) << 32)
                       | (unsigned)(yl * WDIM + x);
                rank[j] = atomicAdd(&lcnt[lb[j]], 1u);
            } else {
                lb[j] = -1;
            }
        }
    }
    __syncthreads();

    if (tid < 128) scan[0][tid] = (tid < LBUCKETS) ? lcnt[tid] : 0u;
    __syncthreads();
    int src = 0;
    for (int off = 1; off < 128; off <<= 1) {
        if (tid < 128) {
            unsigned v = scan[src][tid];
            if (tid >= off) v += scan[src][tid - off];
            scan[src ^ 1][tid] = v;
        }
        src ^= 1;
        __syncthreads();
    }
    if (tid < LBUCKETS) {
        const unsigned c = lcnt[tid];
        lpre[tid]  = scan[src][tid] - c;
        gbase[tid] = c ? atomicAdd(&counts[b * LBUCKETS + tid], c) : 0u;
    }
    __syncthreads();

#pragma unroll
    for (int j = 0; j < 4; ++j) {
        if (lb[j] >= 0) {
            const unsigned s = lpre[lb[j]] + rank[j];
            stage[s] = rec[j];
            slb[s]   = (unsigned char)lb[j];
        }
    }
    __syncthreads();

    const int nblk = (E - e0 < EV_PER_BLOCK) ? (E - e0) : EV_PER_BLOCK;
    for (int s = tid; s < nblk; s += 256) {
        const int l = slb[s];
        const unsigned ofs = gbase[l] + ((unsigned)s - lpre[l]);
        if (ofs < BUCKET_CAP)
            records[(size_t)(b * LBUCKETS + l) * BUCKET_CAP + ofs] = stage[s];
    }
}

// ---------------------------------------------------------------------------
// Kernel 2b: one block (512 threads) per bucket. LDS 62 KB -> 2 blocks/CU.
// Per record: ONE contiguous aligned 96 B read from T9 (rows r and r+1 give
// t0[i], t1[i] for all 9 bins; identical values to the old 18 strided table
// loads -> bit-identical output), 9 interp FMAs + 9 LDS atomics, then
// float2-vectorized copy-out.
// ---------------------------------------------------------------------------
__global__ __launch_bounds__(512) void tile_kernel(
    const unsigned int* __restrict__ counts, const uint2* __restrict__ records,
    const float* __restrict__ t9, float* __restrict__ out)
{
    __shared__ float tile[TILE_ELEMS];
    const int tid = threadIdx.x;
    const int bucket = blockIdx.x;
    const int yt = bucket % TILES_PER_BP;
    const int bp = bucket / TILES_PER_BP;    /* b*2 + pol */

    const int n = min(counts[bucket], (unsigned)BUCKET_CAP);  /* early: overlap latency */
    const uint2* __restrict__ rec = records + (size_t)bucket * BUCKET_CAP;

    {
        float2* __restrict__ t2 = (float2*)tile;
        const float2 z = {0.f, 0.f};
        for (int k = tid; k < TILE_ELEMS / 2; k += 512) t2[k] = z;
    }
    __syncthreads();

    for (int r = tid; r < n; r += 512) {
        const uint2 v = rec[r];
        const int   pix = (int)v.x;
        const float t   = __uint_as_float(v.y);
        const float pos = (t + 1.0f) * ((float)TABLE_N * 0.5f);
        const int   i0  = (int)pos;          /* in [8192, 16384) */
        const float frac = pos - (float)i0;
        const int   rr  = i0 - HALF_N;       /* in [0, 8191] */
        const float4* __restrict__ rowp = (const float4*)(t9 + rr * T9_STRIDE);
        const float4 a0 = rowp[0], a1 = rowp[1], a2 = rowp[2];  /* t0[0..8] (+3 pad) */
        const float4 c0 = rowp[3], c1 = rowp[4], c2 = rowp[5];  /* t1[0..8] (+3 pad) */
        const float t0v[9] = {a0.x, a0.y, a0.z, a0.w, a1.x, a1.y, a1.z, a1.w, a2.x};
        const float t1v[9] = {c0.x, c0.y, c0.z, c0.w, c1.x, c1.y, c1.z, c1.w, c2.x};
#pragma unroll
        for (int i = 0; i < C_BINS; ++i) {
            const float val = t * fmaf(frac, t1v[i] - t0v[i], t0v[i]);
            atomicAdd(&tile[i * (ROWS_PER_TILE * WDIM) + pix], val);
        }
    }
    __syncthreads();

    float* __restrict__ obase = out + (size_t)bp * (C_BINS * WH) + yt * (ROWS_PER_TILE * WDIM);
#pragma unroll
    for (int i = 0; i < C_BINS; ++i) {
        const float2* __restrict__ s2 = (const float2*)&tile[i * (ROWS_PER_TILE * WDIM)];
        float2* __restrict__ d2 = (float2*)(obase + i * WH);
        for (int k = tid; k < ROW_F2; k += 512) d2[k] = s2[k];
    }
}

// ---------------------------------------------------------------------------
// Fallback path (only if ws_size < ~7.3 MB): global-atomic scatter (uses the
// plain table, which is always built).
// ---------------------------------------------------------------------------
__global__ __launch_bounds__(256) void zero_kernel(float4* __restrict__ out, int n4)
{
    int i = blockIdx.x * 256 + threadIdx.x;
    int stride = gridDim.x * 256;
    float4 z = {0.f, 0.f, 0.f, 0.f};
    for (; i < n4; i += stride) out[i] = z;
}

__global__ __launch_bounds__(256) void scatter_kernel(
    const int* __restrict__ xs, const int* __restrict__ ys,
    const float* __restrict__ ts, const int* __restrict__ ps,
    const int* __restrict__ bs, const float* __restrict__ table,
    float* __restrict__ out, int E)
{
    const int e = blockIdx.x * 256 + threadIdx.x;
    if (e >= E) return;
    const int x = xs[e], y = ys[e], p = ps[e], b = bs[e];
    const float t = ts[e];
    int idx0 = x + WDIM * y + (WH * C_BINS) * p + (2 * WH * C_BINS) * b;
#pragma unroll
    for (int i = 0; i < C_BINS; ++i) {
        float u   = t - (float)i * (1.0f / (float)(C_BINS - 1));
        float pos = (u + 1.0f) * ((float)TABLE_N * 0.5f);
        int   i0  = (int)pos;
        i0 = (i0 < 0) ? 0 : ((i0 > TABLE_N - 1) ? TABLE_N - 1 : i0);
        float frac = pos - (float)i0;
        float f  = fmaf(frac, table[i0 + 1] - table[i0], table[i0]);
        int idx = idx0 + WH * i;
        idx = (idx < 0) ? 0 : ((idx >= NUM_VOXELS) ? NUM_VOXELS - 1 : idx);
        atomicAdd(&out[idx], t * f);
    }
}

extern "C" void kernel_launch(void* const* d_in, const int* in_sizes, int n_in,
                              void* d_out, int out_size, void* d_ws, size_t ws_size,
                              hipStream_t stream)
{
    const int*   xs = (const int*)d_in[0];
    const int*   ys = (const int*)d_in[1];
    const float* ts = (const float*)d_in[2];
    const int*   ps = (const int*)d_in[3];
    const int*   bs = (const int*)d_in[4];
    const float* W1 = (const float*)d_in[5];
    const float* b1 = (const float*)d_in[6];
    const float* W2 = (const float*)d_in[7];
    const float* b2 = (const float*)d_in[8];
    const float* W3 = (const float*)d_in[9];
    const float* b3 = (const float*)d_in[10];

    float* out = (float*)d_out;
    char*  ws  = (char*)d_ws;
    float* table = (float*)(ws + WS_TABLE_OFF);
    unsigned int* counts = (unsigned int*)(ws + WS_COUNT_OFF);
    float* t9 = (float*)(ws + WS_T9_OFF);
    const int E = in_sizes[0];
    const int use_fast = (ws_size >= WS_NEEDED) ? 1 : 0;

    build_table_kernel<<<(TABLE_N / 32) + 1, 256, 0, stream>>>(
        W1, b1, W2, b2, W3, b3, table, t9, counts, use_fast);

    if (use_fast) {
        unsigned long long* records = (unsigned long long*)(ws + WS_REC_OFF);
        bucket_kernel<<<(E + EV_PER_BLOCK - 1) / EV_PER_BLOCK, 256, 0, stream>>>(
            xs, ys, ts, ps, counts, records, E);
        tile_kernel<<<NBUCKETS, 512, 0, stream>>>(
            counts, (const uint2*)records, t9, out);
    } else {
        zero_kernel<<<1024, 256, 0, stream>>>((float4*)out, out_size / 4);
        scatter_kernel<<<(E + 255) / 256, 256, 0, stream>>>(
            xs, ys, ts, ps, bs, table, out, E);
    }
}

// Round 2
// 172.678 us; speedup vs baseline: 1.0658x; 1.0550x over previous
//
#include <hip/hip_runtime.h>

#define C_BINS 9
#define H_DIM 260
#define WDIM 346
#define B_DIM 16
#define N_PER_B 32768
#define HIDDEN 100
#define NEG_SLOPE 0.1f
#define WH (WDIM * H_DIM)                         /* 89,960 */
#define NUM_VOXELS (2 * C_BINS * WH * B_DIM)      /* 25,908,480 */
#define TABLE_N 16384                             /* intervals over [-1,1]; TABLE_N+1 entries */
#define HALF_N (TABLE_N / 2)                      /* 8192 */
#define BIN_SHIFT (TABLE_N / 16)                  /* table shift per bin = 1024, exact in fp32 */
#define T9_STRIDE 12                              /* 9 bins padded to 12 floats = 48 B */

#define ROWS_PER_TILE 4                           /* 65 tiles cover 260 rows exactly */
#define TILES_PER_BP 65
#define LBUCKETS (2 * TILES_PER_BP)               /* 130 local buckets (pol, ytile) */
#define NBUCKETS (B_DIM * LBUCKETS)               /* 2080 global buckets */
#define BUCKET_CAP 512                            /* mean 252, sigma ~16 -> 16 sigma margin */
#define EV_PER_BLOCK 1024                         /* divides 32768 */
#define TILE_ELEMS (C_BINS * ROWS_PER_TILE * WDIM)/* 12,456 floats = 49,824 B LDS -> 3 blk/CU */
#define TILE_F4 (TILE_ELEMS / 4)                  /* 3114 */
#define CHUNK_F4 (ROWS_PER_TILE * WDIM / 4)       /* 346 float4 per (bin,tile) chunk */
#define BUILD_BLOCKS (TABLE_N / 32 + 1)           /* 513 */

/* fused-kernel shared memory: union of build (41,632 B) and bucket (12,824 B) */
#define SMEM_BYTES 41632
#define SM_STAGE 0        /* 1024 x u64  = 8192 */
#define SM_SCAN  8192     /* 2 x 256 x u32 = 2048 */
#define SM_LCNT  10240    /* 130 x u32 = 520 */
#define SM_LPRE  10760
#define SM_GBASE 11280
#define SM_SLB   11800    /* 1024 x u8 */

// workspace layout (bytes)
#define WS_TABLE_OFF 0                                     /* (TABLE_N+1)*4 = 65,540 */
#define WS_COUNT_OFF 66048                                 /* NBUCKETS*4 = 8,320 */
#define WS_T9_OFF    74752                                 /* (HALF_N+1)*12*4 = 393,264 */
#define WS_REC_OFF   468480
#define WS_REC_SZ    ((size_t)NBUCKETS * BUCKET_CAP * 8)   /* 8,519,680 */
#define WS_NEEDED    (WS_REC_OFF + WS_REC_SZ)              /* ~9.0 MB */

// ---------------------------------------------------------------------------
// Fused kernel: blocks [0, n_bucket_blocks) run the event-bucketing scatter;
// blocks [n_bucket_blocks, +BUILD_BLOCKS) tabulate the MLP. The two phases
// are data-independent (counts pre-zeroed by hipMemsetAsync), so fusing them
// overlaps ~4 us of build behind the bucket pass and removes one
// serialization gap. LDS is a 41.6 KB union -> 3 blocks/CU.
//
// Build half: 8 threads/entry (quad over k-rows x duo over j-halves), 32
// entries/block. Writes table[] (fallback) and the packed interp rows
// T9[r][i] = table[r + 8192 - 1024*i] so tile_kernel reads ONE contiguous
// 96 B block per record.
//
// Bucket half: one block owns 1024 consecutive events (one batch -> 130
// local buckets). int4/float4 event loads, LDS count -> 256-wide prefix ->
// ONE global atomicAdd per non-empty bucket -> records staged bucket-sorted
// in LDS -> contiguous copy-out.
// ---------------------------------------------------------------------------
__global__ __launch_bounds__(256) void fused_build_bucket_kernel(
    const int* __restrict__ xs, const int* __restrict__ ys,
    const float* __restrict__ ts, const int* __restrict__ ps,
    const float* __restrict__ W1, const float* __restrict__ b1,
    const float* __restrict__ W2, const float* __restrict__ b2,
    const float* __restrict__ W3, const float* __restrict__ b3,
    float* __restrict__ table, float* __restrict__ t9,
    unsigned int* __restrict__ counts,
    unsigned long long* __restrict__ records,
    int E, int n_bucket_blocks, int write_t9)
{
    __shared__ __align__(16) char smem[SMEM_BYTES];
    const int tid = threadIdx.x;

    if (blockIdx.x < (unsigned)n_bucket_blocks) {
        // ------------------------------ bucket path ------------------------
        unsigned long long* stage = (unsigned long long*)(smem + SM_STAGE);
        unsigned*      scan  = (unsigned*)(smem + SM_SCAN);
        unsigned*      lcnt  = (unsigned*)(smem + SM_LCNT);
        unsigned*      lpre  = (unsigned*)(smem + SM_LPRE);
        unsigned*      gbase = (unsigned*)(smem + SM_GBASE);
        unsigned char* slb   = (unsigned char*)(smem + SM_SLB);

        const int e0 = blockIdx.x * EV_PER_BLOCK;
        const int b  = e0 >> 15;   /* whole block lies in one batch: 1024 | 32768 */

        for (int i = tid; i < LBUCKETS; i += 256) lcnt[i] = 0;
        __syncthreads();

        int lb[4];
        unsigned rank[4];
        unsigned long long rec[4];
        const int eb = e0 + tid * 4;
        if (eb + 3 < E) {
            const int v4 = (e0 >> 2) + tid;
            const int4   xv = ((const int4*)xs)[v4];
            const int4   yv = ((const int4*)ys)[v4];
            const int4   pv = ((const int4*)ps)[v4];
            const float4 tv = ((const float4*)ts)[v4];
            const int   xa[4] = {xv.x, xv.y, xv.z, xv.w};
            const int   ya[4] = {yv.x, yv.y, yv.z, yv.w};
            const int   pa[4] = {pv.x, pv.y, pv.z, pv.w};
            const float ta[4] = {tv.x, tv.y, tv.z, tv.w};
#pragma unroll
            for (int j = 0; j < 4; ++j) {
                const int yt = ya[j] >> 2;             /* ROWS_PER_TILE = 4 */
                const int yl = ya[j] & 3;
                lb[j]  = pa[j] * TILES_PER_BP + yt;
                rec[j] = ((unsigned long long)__float_as_uint(ta[j]) << 32)
                       | (unsigned)(yl * WDIM + xa[j]);
                rank[j] = atomicAdd(&lcnt[lb[j]], 1u);
            }
        } else {
#pragma unroll
            for (int j = 0; j < 4; ++j) {
                const int e = eb + j;
                if (e < E) {
                    const int   x = xs[e];
                    const int   y = ys[e];
                    const int   p = ps[e];
                    const float t = ts[e];
                    const int  yt = y >> 2;
                    const int  yl = y & 3;
                    lb[j]  = p * TILES_PER_BP + yt;
                    rec[j] = ((unsigned long long)__float_as_uint(t) << 32)
                           | (unsigned)(yl * WDIM + x);
                    rank[j] = atomicAdd(&lcnt[lb[j]], 1u);
                } else {
                    lb[j] = -1;
                }
            }
        }
        __syncthreads();

        scan[tid] = (tid < LBUCKETS) ? lcnt[tid] : 0u;
        __syncthreads();
        int src = 0;
        for (int off = 1; off < 256; off <<= 1) {
            unsigned v = scan[src * 256 + tid];
            if (tid >= off) v += scan[src * 256 + tid - off];
            scan[(src ^ 1) * 256 + tid] = v;
            src ^= 1;
            __syncthreads();
        }
        if (tid < LBUCKETS) {
            const unsigned c = lcnt[tid];
            lpre[tid]  = scan[src * 256 + tid] - c;
            gbase[tid] = c ? atomicAdd(&counts[b * LBUCKETS + tid], c) : 0u;
        }
        __syncthreads();

#pragma unroll
        for (int j = 0; j < 4; ++j) {
            if (lb[j] >= 0) {
                const unsigned s = lpre[lb[j]] + rank[j];
                stage[s] = rec[j];
                slb[s]   = (unsigned char)lb[j];
            }
        }
        __syncthreads();

        const int nblk = (E - e0 < EV_PER_BLOCK) ? (E - e0) : EV_PER_BLOCK;
        for (int s = tid; s < nblk; s += 256) {
            const int l = slb[s];
            const unsigned ofs = gbase[l] + ((unsigned)s - lpre[l]);
            if (ofs < BUCKET_CAP)
                records[(size_t)(b * LBUCKETS + l) * BUCKET_CAP + ofs] = stage[s];
        }
    } else {
        // ------------------------------ build path -------------------------
        float* sW2 = (float*)smem;                       /* 10,008 floats */
        float* sW1 = (float*)(smem + 40032);
        float* sb1 = sW1 + HIDDEN;
        float* sb2 = sb1 + HIDDEN;
        float* sW3 = sb2 + HIDDEN;

        {
            const float4* __restrict__ srcw = (const float4*)W2;
            float4* dst = (float4*)sW2;
            for (int i = tid; i < (HIDDEN * HIDDEN) / 4; i += 256) dst[i] = srcw[i];
        }
        if (tid < 8) sW2[HIDDEN * HIDDEN + tid] = 0.0f;  /* finite pad (0*NaN = NaN) */
        if (tid < HIDDEN) {
            sW1[tid] = W1[tid];
            sb1[tid] = b1[tid];
            sb2[tid] = b2[tid];
            sW3[tid] = W3[tid];
        }
        __syncthreads();

        const int entry_local = tid >> 3;                /* 32 entries per block */
        const int o  = tid & 7;
        const int q  = o & 3;                            /* k-residue */
        const int j0 = (o >> 2) * 52;                    /* j-half start: 0 or 52 */
        const int g  = (blockIdx.x - n_bucket_blocks) * 32 + entry_local;
        if (g > TABLE_N) return;
        const float u = -1.0f + (2.0f / (float)TABLE_N) * (float)g;

        float h1[52];
#pragma unroll
        for (int j = 0; j < 52; ++j) {
            const int jj = j0 + j;
            float v = (jj < HIDDEN) ? fmaf(u, sW1[jj], sb1[jj]) : 0.0f;
            h1[j] = (v >= 0.0f) ? v : NEG_SLOPE * v;
        }

        float acc = 0.0f;
        for (int k = q; k < HIDDEN; k += 4) {
            const float* __restrict__ row = &sW2[k * HIDDEN + j0];
            float a0 = 0.f, a1 = 0.f, a2 = 0.f, a3 = 0.f;
#pragma unroll
            for (int j = 0; j < 52; j += 4) {
                a0 = fmaf(row[j + 0], h1[j + 0], a0);
                a1 = fmaf(row[j + 1], h1[j + 1], a1);
                a2 = fmaf(row[j + 2], h1[j + 2], a2);
                a3 = fmaf(row[j + 3], h1[j + 3], a3);
            }
            float part = (a0 + a1) + (a2 + a3);
            part += __shfl_xor(part, 4);                 /* combine j-halves */
            float a = sb2[k] + part;
            a = (a >= 0.0f) ? a : NEG_SLOPE * a;
            acc = fmaf(a, sW3[k], acc);
        }
        acc += __shfl_xor(acc, 1);                       /* combine k-quads */
        acc += __shfl_xor(acc, 2);
        if (o == 0) {
            const float val = acc + b3[0];
            table[g] = val;
            if (write_t9) {
#pragma unroll
                for (int i = 0; i < C_BINS; ++i) {
                    const int r = g - HALF_N + BIN_SHIFT * i;
                    if (r >= 0 && r <= HALF_N) t9[r * T9_STRIDE + i] = val;
                }
            }
        }
    }
}

// ---------------------------------------------------------------------------
// Tile kernel: one block (512 threads) per bucket. LDS 49.8 KB -> 3 blocks/CU
// (24 waves/CU over the HBM-write-bound phase). Per record: ONE contiguous
// aligned 96 B read from T9 (t0[i], t1[i] for all 9 bins), 9 interp FMAs +
// 9 LDS atomics, then float4 zero / float4 copy-out (chunk = 5,536 B is
// 16 B-aligned for every yt with ROWS_PER_TILE = 4).
// ---------------------------------------------------------------------------
__global__ __launch_bounds__(512) void tile_kernel(
    const unsigned int* __restrict__ counts, const uint2* __restrict__ records,
    const float* __restrict__ t9, float* __restrict__ out)
{
    __shared__ __align__(16) float tile[TILE_ELEMS];
    const int tid = threadIdx.x;
    const int bucket = blockIdx.x;
    const int yt = bucket % TILES_PER_BP;
    const int bp = bucket / TILES_PER_BP;    /* b*2 + pol */

    const int n = min(counts[bucket], (unsigned)BUCKET_CAP);  /* early: overlap latency */
    const uint2* __restrict__ rec = records + (size_t)bucket * BUCKET_CAP;

    float4* __restrict__ t4 = (float4*)tile;
    {
        const float4 z = {0.f, 0.f, 0.f, 0.f};
        for (int k = tid; k < TILE_F4; k += 512) t4[k] = z;
    }
    __syncthreads();

    for (int r = tid; r < n; r += 512) {
        const uint2 v = rec[r];
        const int   pix = (int)v.x;
        const float t   = __uint_as_float(v.y);
        const float pos = (t + 1.0f) * ((float)TABLE_N * 0.5f);
        const int   i0  = (int)pos;          /* in [8192, 16384) */
        const float frac = pos - (float)i0;
        const int   rr  = i0 - HALF_N;       /* in [0, 8191] */
        const float4* __restrict__ rowp = (const float4*)(t9 + rr * T9_STRIDE);
        const float4 a0 = rowp[0], a1 = rowp[1], a2 = rowp[2];  /* t0[0..8] (+3 pad) */
        const float4 c0 = rowp[3], c1 = rowp[4], c2 = rowp[5];  /* t1[0..8] (+3 pad) */
        const float t0v[9] = {a0.x, a0.y, a0.z, a0.w, a1.x, a1.y, a1.z, a1.w, a2.x};
        const float t1v[9] = {c0.x, c0.y, c0.z, c0.w, c1.x, c1.y, c1.z, c1.w, c2.x};
#pragma unroll
        for (int i = 0; i < C_BINS; ++i) {
            const float val = t * fmaf(frac, t1v[i] - t0v[i], t0v[i]);
            atomicAdd(&tile[i * (ROWS_PER_TILE * WDIM) + pix], val);
        }
    }
    __syncthreads();

    float* __restrict__ obase = out + (size_t)bp * (C_BINS * WH)
                              + yt * (ROWS_PER_TILE * WDIM);
    for (int s = tid; s < TILE_F4; s += 512) {
        const int i = s / CHUNK_F4;
        const int k = s - i * CHUNK_F4;
        ((float4*)(obase + i * WH))[k] = t4[i * CHUNK_F4 + k];
    }
}

// ---------------------------------------------------------------------------
// Fallback path (only if ws_size < ~9 MB): global-atomic scatter (uses the
// plain table, which is always built).
// ---------------------------------------------------------------------------
__global__ __launch_bounds__(256) void zero_kernel(float4* __restrict__ out, int n4)
{
    int i = blockIdx.x * 256 + threadIdx.x;
    int stride = gridDim.x * 256;
    float4 z = {0.f, 0.f, 0.f, 0.f};
    for (; i < n4; i += stride) out[i] = z;
}

__global__ __launch_bounds__(256) void scatter_kernel(
    const int* __restrict__ xs, const int* __restrict__ ys,
    const float* __restrict__ ts, const int* __restrict__ ps,
    const int* __restrict__ bs, const float* __restrict__ table,
    float* __restrict__ out, int E)
{
    const int e = blockIdx.x * 256 + threadIdx.x;
    if (e >= E) return;
    const int x = xs[e], y = ys[e], p = ps[e], b = bs[e];
    const float t = ts[e];
    int idx0 = x + WDIM * y + (WH * C_BINS) * p + (2 * WH * C_BINS) * b;
#pragma unroll
    for (int i = 0; i < C_BINS; ++i) {
        float u   = t - (float)i * (1.0f / (float)(C_BINS - 1));
        float pos = (u + 1.0f) * ((float)TABLE_N * 0.5f);
        int   i0  = (int)pos;
        i0 = (i0 < 0) ? 0 : ((i0 > TABLE_N - 1) ? TABLE_N - 1 : i0);
        float frac = pos - (float)i0;
        float f  = fmaf(frac, table[i0 + 1] - table[i0], table[i0]);
        int idx = idx0 + WH * i;
        idx = (idx < 0) ? 0 : ((idx >= NUM_VOXELS) ? NUM_VOXELS - 1 : idx);
        atomicAdd(&out[idx], t * f);
    }
}

extern "C" void kernel_launch(void* const* d_in, const int* in_sizes, int n_in,
                              void* d_out, int out_size, void* d_ws, size_t ws_size,
                              hipStream_t stream)
{
    const int*   xs = (const int*)d_in[0];
    const int*   ys = (const int*)d_in[1];
    const float* ts = (const float*)d_in[2];
    const int*   ps = (const int*)d_in[3];
    const int*   bs = (const int*)d_in[4];
    const float* W1 = (const float*)d_in[5];
    const float* b1 = (const float*)d_in[6];
    const float* W2 = (const float*)d_in[7];
    const float* b2 = (const float*)d_in[8];
    const float* W3 = (const float*)d_in[9];
    const float* b3 = (const float*)d_in[10];

    float* out = (float*)d_out;
    char*  ws  = (char*)d_ws;
    float* table = (float*)(ws + WS_TABLE_OFF);
    unsigned int* counts = (unsigned int*)(ws + WS_COUNT_OFF);
    float* t9 = (float*)(ws + WS_T9_OFF);
    const int E = in_sizes[0];
    const int use_fast = (ws_size >= WS_NEEDED) ? 1 : 0;

    if (use_fast) {
        unsigned long long* records = (unsigned long long*)(ws + WS_REC_OFF);
        const int nbB = (E + EV_PER_BLOCK - 1) / EV_PER_BLOCK;   /* 512 */
        hipMemsetAsync(counts, 0, NBUCKETS * sizeof(unsigned int), stream);
        fused_build_bucket_kernel<<<nbB + BUILD_BLOCKS, 256, 0, stream>>>(
            xs, ys, ts, ps, W1, b1, W2, b2, W3, b3,
            table, t9, counts, records, E, nbB, 1);
        tile_kernel<<<NBUCKETS, 512, 0, stream>>>(
            counts, (const uint2*)records, t9, out);
    } else {
        fused_build_bucket_kernel<<<BUILD_BLOCKS, 256, 0, stream>>>(
            xs, ys, ts, ps, W1, b1, W2, b2, W3, b3,
            table, t9, counts, (unsigned long long*)out /*unused*/, E, 0, 0);
        zero_kernel<<<1024, 256, 0, stream>>>((float4*)out, out_size / 4);
        scatter_kernel<<<(E + 255) / 256, 256, 0, stream>>>(
            xs, ys, ts, ps, bs, table, out, E);
    }
}

// Round 3
// 171.639 us; speedup vs baseline: 1.0722x; 1.0060x over previous
//
#include <hip/hip_runtime.h>

#define C_BINS 9
#define H_DIM 260
#define WDIM 346
#define B_DIM 16
#define N_PER_B 32768
#define HIDDEN 100
#define NEG_SLOPE 0.1f
#define WH (WDIM * H_DIM)                         /* 89,960 */
#define NUM_VOXELS (2 * C_BINS * WH * B_DIM)      /* 25,908,480 */
#define TABLE_N 16384                             /* intervals over [-1,1]; TABLE_N+1 entries */
#define HALF_N (TABLE_N / 2)                      /* 8192 */
#define BIN_SHIFT (TABLE_N / 16)                  /* table shift per bin = 1024, exact in fp32 */
#define T9_STRIDE 12                              /* 9 bins padded to 12 floats = 48 B */

#define ROWS_PER_TILE 4                           /* 65 tiles cover 260 rows exactly */
#define TILES_PER_BP 65
#define LBUCKETS (2 * TILES_PER_BP)               /* 130 local buckets (pol, ytile) */
#define NBUCKETS (B_DIM * LBUCKETS)               /* 2080 tile blocks */
#define EV_PER_BLOCK 1024                         /* divides 32768 */
#define BLOCKS_PER_BATCH (N_PER_B / EV_PER_BLOCK) /* 32 */
#define PRE_STRIDE 132                            /* 131 u16 prefix entries, padded */
#define TILE_ELEMS (C_BINS * ROWS_PER_TILE * WDIM)/* 12,456 floats = 49,824 B LDS -> 3 blk/CU */
#define TILE_F4 (TILE_ELEMS / 4)                  /* 3114 */
#define CHUNK_F4 (ROWS_PER_TILE * WDIM / 4)       /* 346 float4 per (bin,tile) chunk */
#define BUILD_BLOCKS (TABLE_N / 32 + 1)           /* 513 */

/* fused-kernel shared memory: union of build (41,632 B) and bucket (11,280 B) */
#define SMEM_BYTES 41632
#define SM_STAGE 0        /* 1024 x u64  = 8192 (16B-aligned for ulonglong2) */
#define SM_SCAN  8192     /* 2 x 256 x u32 = 2048 */
#define SM_LCNT  10240    /* 130 x u32 = 520 */
#define SM_LPRE  10760    /* 130 x u32 = 520 */

// workspace layout (bytes). Deterministic record layout: bucket-block g owns
// records[g*1024 .. g*1024+1023] (bucket-sorted within the segment) and
// publishes a 131-entry u16 prefix table -> no counts array, no memset, no
// global atomics, no overflow risk.
#define WS_TABLE_OFF 0                                     /* (TABLE_N+1)*4 = 65,540 */
#define WS_T9_OFF    66048                                 /* (HALF_N+1)*12*4 = 393,264 */
#define WS_PRE_OFF   459392                                /* 512*132*2 = 135,168 */
#define WS_REC_OFF   614400                                /* 16B-aligned */
#define WS_REC_SZ    ((size_t)B_DIM * N_PER_B * 8)         /* 4,194,304 */
#define WS_NEEDED    (WS_REC_OFF + WS_REC_SZ)              /* ~4.8 MB */

// ---------------------------------------------------------------------------
// Fused kernel: blocks [0, n_bucket_blocks) bucket-sort their 1024 events;
// blocks [n_bucket_blocks, +BUILD_BLOCKS) tabulate the MLP. Data-independent
// halves -> build overlaps behind the bucket pass. LDS union -> 3 blocks/CU.
//
// Bucket half: int4/float4 event loads, LDS count -> 256-wide prefix ->
// records staged bucket-sorted in LDS -> ulonglong2-coalesced copy to the
// block's OWN 1024-record segment + u16 prefix table. No global atomics.
//
// Build half: 8 threads/entry (quad over k-rows x duo over j-halves), 32
// entries/block. Writes table[] (fallback) and packed interp rows
// T9[r][i] = table[r + 8192 - 1024*i] so tile_kernel reads ONE contiguous
// 96 B block per record.
// ---------------------------------------------------------------------------
__global__ __launch_bounds__(256) void fused_build_bucket_kernel(
    const int* __restrict__ xs, const int* __restrict__ ys,
    const float* __restrict__ ts, const int* __restrict__ ps,
    const float* __restrict__ W1, const float* __restrict__ b1,
    const float* __restrict__ W2, const float* __restrict__ b2,
    const float* __restrict__ W3, const float* __restrict__ b3,
    float* __restrict__ table, float* __restrict__ t9,
    unsigned short* __restrict__ pre,
    unsigned long long* __restrict__ records,
    int E, int n_bucket_blocks)
{
    __shared__ __align__(16) char smem[SMEM_BYTES];
    const int tid = threadIdx.x;

    if (blockIdx.x < (unsigned)n_bucket_blocks) {
        // ------------------------------ bucket path ------------------------
        unsigned long long* stage = (unsigned long long*)(smem + SM_STAGE);
        unsigned* scan = (unsigned*)(smem + SM_SCAN);
        unsigned* lcnt = (unsigned*)(smem + SM_LCNT);
        unsigned* lpre = (unsigned*)(smem + SM_LPRE);

        const int g  = blockIdx.x;
        const int e0 = g * EV_PER_BLOCK;

        for (int i = tid; i < LBUCKETS; i += 256) lcnt[i] = 0;
        __syncthreads();

        int lb[4];
        unsigned rank[4];
        unsigned long long rec[4];
        const int eb = e0 + tid * 4;
        if (eb + 3 < E) {
            const int v4 = (e0 >> 2) + tid;
            const int4   xv = ((const int4*)xs)[v4];
            const int4   yv = ((const int4*)ys)[v4];
            const int4   pv = ((const int4*)ps)[v4];
            const float4 tv = ((const float4*)ts)[v4];
            const int   xa[4] = {xv.x, xv.y, xv.z, xv.w};
            const int   ya[4] = {yv.x, yv.y, yv.z, yv.w};
            const int   pa[4] = {pv.x, pv.y, pv.z, pv.w};
            const float ta[4] = {tv.x, tv.y, tv.z, tv.w};
#pragma unroll
            for (int j = 0; j < 4; ++j) {
                const int yt = ya[j] >> 2;             /* ROWS_PER_TILE = 4 */
                const int yl = ya[j] & 3;
                lb[j]  = pa[j] * TILES_PER_BP + yt;
                rec[j] = ((unsigned long long)__float_as_uint(ta[j]) << 32)
                       | (unsigned)(yl * WDIM + xa[j]);
                rank[j] = atomicAdd(&lcnt[lb[j]], 1u);
            }
        } else {
#pragma unroll
            for (int j = 0; j < 4; ++j) {
                const int e = eb + j;
                if (e < E) {
                    const int   x = xs[e];
                    const int   y = ys[e];
                    const int   p = ps[e];
                    const float t = ts[e];
                    const int  yt = y >> 2;
                    const int  yl = y & 3;
                    lb[j]  = p * TILES_PER_BP + yt;
                    rec[j] = ((unsigned long long)__float_as_uint(t) << 32)
                           | (unsigned)(yl * WDIM + x);
                    rank[j] = atomicAdd(&lcnt[lb[j]], 1u);
                } else {
                    lb[j] = -1;
                }
            }
        }
        __syncthreads();

        scan[tid] = (tid < LBUCKETS) ? lcnt[tid] : 0u;
        __syncthreads();
        int src = 0;
        for (int off = 1; off < 256; off <<= 1) {
            unsigned v = scan[src * 256 + tid];
            if (tid >= off) v += scan[src * 256 + tid - off];
            scan[(src ^ 1) * 256 + tid] = v;
            src ^= 1;
            __syncthreads();
        }
        const int nblk = (E - e0 < EV_PER_BLOCK) ? (E - e0) : EV_PER_BLOCK;
        if (tid < LBUCKETS)
            lpre[tid] = scan[src * 256 + tid] - lcnt[tid];   /* exclusive prefix */
        if (tid <= LBUCKETS)
            pre[g * PRE_STRIDE + tid] =
                (unsigned short)((tid < LBUCKETS) ? (scan[src * 256 + tid] - lcnt[tid])
                                                  : (unsigned)nblk);
        __syncthreads();

#pragma unroll
        for (int j = 0; j < 4; ++j) {
            if (lb[j] >= 0) stage[lpre[lb[j]] + rank[j]] = rec[j];
        }
        __syncthreads();

        unsigned long long* __restrict__ dst = records + (size_t)g * EV_PER_BLOCK;
        if (nblk == EV_PER_BLOCK) {
            ulonglong2* __restrict__ d2 = (ulonglong2*)dst;
            const ulonglong2* __restrict__ s2 = (const ulonglong2*)stage;
#pragma unroll
            for (int s = tid; s < EV_PER_BLOCK / 2; s += 256) d2[s] = s2[s];
        } else {
            for (int s = tid; s < nblk; s += 256) dst[s] = stage[s];
        }
    } else {
        // ------------------------------ build path -------------------------
        float* sW2 = (float*)smem;                       /* 10,008 floats */
        float* sW1 = (float*)(smem + 40032);
        float* sb1 = sW1 + HIDDEN;
        float* sb2 = sb1 + HIDDEN;
        float* sW3 = sb2 + HIDDEN;

        {
            const float4* __restrict__ srcw = (const float4*)W2;
            float4* dst = (float4*)sW2;
            for (int i = tid; i < (HIDDEN * HIDDEN) / 4; i += 256) dst[i] = srcw[i];
        }
        if (tid < 8) sW2[HIDDEN * HIDDEN + tid] = 0.0f;  /* finite pad (0*NaN = NaN) */
        if (tid < HIDDEN) {
            sW1[tid] = W1[tid];
            sb1[tid] = b1[tid];
            sb2[tid] = b2[tid];
            sW3[tid] = W3[tid];
        }
        __syncthreads();

        const int entry_local = tid >> 3;                /* 32 entries per block */
        const int o  = tid & 7;
        const int q  = o & 3;                            /* k-residue */
        const int j0 = (o >> 2) * 52;                    /* j-half start: 0 or 52 */
        const int g  = (blockIdx.x - n_bucket_blocks) * 32 + entry_local;
        if (g > TABLE_N) return;
        const float u = -1.0f + (2.0f / (float)TABLE_N) * (float)g;

        float h1[52];
#pragma unroll
        for (int j = 0; j < 52; ++j) {
            const int jj = j0 + j;
            float v = (jj < HIDDEN) ? fmaf(u, sW1[jj], sb1[jj]) : 0.0f;
            h1[j] = (v >= 0.0f) ? v : NEG_SLOPE * v;
        }

        float acc = 0.0f;
        for (int k = q; k < HIDDEN; k += 4) {
            const float* __restrict__ row = &sW2[k * HIDDEN + j0];
            float a0 = 0.f, a1 = 0.f, a2 = 0.f, a3 = 0.f;
#pragma unroll
            for (int j = 0; j < 52; j += 4) {
                a0 = fmaf(row[j + 0], h1[j + 0], a0);
                a1 = fmaf(row[j + 1], h1[j + 1], a1);
                a2 = fmaf(row[j + 2], h1[j + 2], a2);
                a3 = fmaf(row[j + 3], h1[j + 3], a3);
            }
            float part = (a0 + a1) + (a2 + a3);
            part += __shfl_xor(part, 4);                 /* combine j-halves */
            float a = sb2[k] + part;
            a = (a >= 0.0f) ? a : NEG_SLOPE * a;
            acc = fmaf(a, sW3[k], acc);
        }
        acc += __shfl_xor(acc, 1);                       /* combine k-quads */
        acc += __shfl_xor(acc, 2);
        if (o == 0) {
            const float val = acc + b3[0];
            table[g] = val;
#pragma unroll
            for (int i = 0; i < C_BINS; ++i) {
                const int r = g - HALF_N + BIN_SHIFT * i;
                if (r >= 0 && r <= HALF_N) t9[r * T9_STRIDE + i] = val;
            }
        }
    }
}

// ---------------------------------------------------------------------------
// Tile kernel: one block (512 threads) per (batch, pol, ytile) bucket.
// LDS 49.8 KB -> 3 blocks/CU. Records gathered from the batch's 32 fixed
// segments: seg = tid>>4, 16 lanes walk [lo,hi) from the u16 prefix table
// (mean 7.9 records/segment -> one iteration). Per record: ONE contiguous
// aligned 96 B read from T9 (t0[i], t1[i] for all 9 bins), 9 interp FMAs +
// 9 LDS atomics, then float4 zero / float4 copy-out.
// ---------------------------------------------------------------------------
__global__ __launch_bounds__(512) void tile_kernel(
    const unsigned short* __restrict__ pre, const uint2* __restrict__ records,
    const float* __restrict__ t9, float* __restrict__ out)
{
    __shared__ __align__(16) float tile[TILE_ELEMS];
    const int tid = threadIdx.x;
    const int bucket = blockIdx.x;           /* b*130 + l */
    const int b = bucket / LBUCKETS;
    const int l = bucket - b * LBUCKETS;
    const int p  = (l >= TILES_PER_BP) ? 1 : 0;
    const int yt = l - p * TILES_PER_BP;
    const int bp = b * 2 + p;

    const int seg  = tid >> 4;               /* 0..31 */
    const int lane = tid & 15;
    const int g    = b * BLOCKS_PER_BATCH + seg;
    const int lo   = pre[g * PRE_STRIDE + l];
    const int hi   = pre[g * PRE_STRIDE + l + 1];
    const uint2* __restrict__ segrec = records + (size_t)g * EV_PER_BLOCK;

    float4* __restrict__ t4 = (float4*)tile;
    {
        const float4 z = {0.f, 0.f, 0.f, 0.f};
        for (int k = tid; k < TILE_F4; k += 512) t4[k] = z;
    }
    __syncthreads();

    for (int r = lo + lane; r < hi; r += 16) {
        const uint2 v = segrec[r];
        const int   pix = (int)v.x;
        const float t   = __uint_as_float(v.y);
        const float pos = (t + 1.0f) * ((float)TABLE_N * 0.5f);
        const int   i0  = (int)pos;          /* in [8192, 16384) */
        const float frac = pos - (float)i0;
        const int   rr  = i0 - HALF_N;       /* in [0, 8191] */
        const float4* __restrict__ rowp = (const float4*)(t9 + rr * T9_STRIDE);
        const float4 a0 = rowp[0], a1 = rowp[1], a2 = rowp[2];  /* t0[0..8] (+3 pad) */
        const float4 c0 = rowp[3], c1 = rowp[4], c2 = rowp[5];  /* t1[0..8] (+3 pad) */
        const float t0v[9] = {a0.x, a0.y, a0.z, a0.w, a1.x, a1.y, a1.z, a1.w, a2.x};
        const float t1v[9] = {c0.x, c0.y, c0.z, c0.w, c1.x, c1.y, c1.z, c1.w, c2.x};
#pragma unroll
        for (int i = 0; i < C_BINS; ++i) {
            const float val = t * fmaf(frac, t1v[i] - t0v[i], t0v[i]);
            atomicAdd(&tile[i * (ROWS_PER_TILE * WDIM) + pix], val);
        }
    }
    __syncthreads();

    float* __restrict__ obase = out + (size_t)bp * (C_BINS * WH)
                              + yt * (ROWS_PER_TILE * WDIM);
    for (int s = tid; s < TILE_F4; s += 512) {
        const int i = s / CHUNK_F4;
        const int k = s - i * CHUNK_F4;
        ((float4*)(obase + i * WH))[k] = t4[i * CHUNK_F4 + k];
    }
}

// ---------------------------------------------------------------------------
// Fallback path (ws too small or unexpected E): global-atomic scatter using
// the plain table (always built).
// ---------------------------------------------------------------------------
__global__ __launch_bounds__(256) void zero_kernel(float4* __restrict__ out, int n4)
{
    int i = blockIdx.x * 256 + threadIdx.x;
    int stride = gridDim.x * 256;
    float4 z = {0.f, 0.f, 0.f, 0.f};
    for (; i < n4; i += stride) out[i] = z;
}

__global__ __launch_bounds__(256) void scatter_kernel(
    const int* __restrict__ xs, const int* __restrict__ ys,
    const float* __restrict__ ts, const int* __restrict__ ps,
    const int* __restrict__ bs, const float* __restrict__ table,
    float* __restrict__ out, int E)
{
    const int e = blockIdx.x * 256 + threadIdx.x;
    if (e >= E) return;
    const int x = xs[e], y = ys[e], p = ps[e], b = bs[e];
    const float t = ts[e];
    int idx0 = x + WDIM * y + (WH * C_BINS) * p + (2 * WH * C_BINS) * b;
#pragma unroll
    for (int i = 0; i < C_BINS; ++i) {
        float u   = t - (float)i * (1.0f / (float)(C_BINS - 1));
        float pos = (u + 1.0f) * ((float)TABLE_N * 0.5f);
        int   i0  = (int)pos;
        i0 = (i0 < 0) ? 0 : ((i0 > TABLE_N - 1) ? TABLE_N - 1 : i0);
        float frac = pos - (float)i0;
        float f  = fmaf(frac, table[i0 + 1] - table[i0], table[i0]);
        int idx = idx0 + WH * i;
        idx = (idx < 0) ? 0 : ((idx >= NUM_VOXELS) ? NUM_VOXELS - 1 : idx);
        atomicAdd(&out[idx], t * f);
    }
}

extern "C" void kernel_launch(void* const* d_in, const int* in_sizes, int n_in,
                              void* d_out, int out_size, void* d_ws, size_t ws_size,
                              hipStream_t stream)
{
    const int*   xs = (const int*)d_in[0];
    const int*   ys = (const int*)d_in[1];
    const float* ts = (const float*)d_in[2];
    const int*   ps = (const int*)d_in[3];
    const int*   bs = (const int*)d_in[4];
    const float* W1 = (const float*)d_in[5];
    const float* b1 = (const float*)d_in[6];
    const float* W2 = (const float*)d_in[7];
    const float* b2 = (const float*)d_in[8];
    const float* W3 = (const float*)d_in[9];
    const float* b3 = (const float*)d_in[10];

    float* out = (float*)d_out;
    char*  ws  = (char*)d_ws;
    float* table = (float*)(ws + WS_TABLE_OFF);
    float* t9 = (float*)(ws + WS_T9_OFF);
    unsigned short* pre = (unsigned short*)(ws + WS_PRE_OFF);
    const int E = in_sizes[0];
    const int use_fast = (ws_size >= WS_NEEDED) && (E == B_DIM * N_PER_B);

    if (use_fast) {
        unsigned long long* records = (unsigned long long*)(ws + WS_REC_OFF);
        const int nbB = E / EV_PER_BLOCK;                        /* 512 */
        fused_build_bucket_kernel<<<nbB + BUILD_BLOCKS, 256, 0, stream>>>(
            xs, ys, ts, ps, W1, b1, W2, b2, W3, b3,
            table, t9, pre, records, E, nbB);
        tile_kernel<<<NBUCKETS, 512, 0, stream>>>(
            pre, (const uint2*)records, t9, out);
    } else {
        fused_build_bucket_kernel<<<BUILD_BLOCKS, 256, 0, stream>>>(
            xs, ys, ts, ps, W1, b1, W2, b2, W3, b3,
            table, t9, pre, (unsigned long long*)out /*unused*/, E, 0);
        zero_kernel<<<1024, 256, 0, stream>>>((float4*)out, out_size / 4);
        scatter_kernel<<<(E + 255) / 256, 256, 0, stream>>>(
            xs, ys, ts, ps, bs, table, out, E);
    }
}